// Round 6
// baseline (4027.116 us; speedup 1.0000x reference)
//
#include <hip/hip_runtime.h>
#include <hip/hip_bf16.h>
#include <stdint.h>
#include <stddef.h>

#define T_LEN 512
#define B_SZ  256
#define I_SZ  256
#define H_SZ  1024
#define NGRP  16   // blocks per barrier group (one batch-group)

typedef __attribute__((ext_vector_type(8))) short bf16x8;
typedef __attribute__((ext_vector_type(4))) float f32x4;
typedef __attribute__((ext_vector_type(4))) unsigned int u32x4;
typedef unsigned short u16;
typedef unsigned int   u32;
typedef unsigned long long u64;

__device__ inline u16 f2bf(float f) {
  union { float f; u32 u; } x; x.f = f;
  u32 r = x.u + 0x7fffu + ((x.u >> 16) & 1u);
  return (u16)(r >> 16);
}

#define GLDS16(gp, lp) __builtin_amdgcn_global_load_lds( \
    (const __attribute__((address_space(1))) u32*)(gp),  \
    (__attribute__((address_space(3))) u32*)(lp), 16, 0, 0)

// keep 8 bf16x8 values pinned in VGPRs (0 instructions)
#define PIN8(B, i) asm volatile("" : "+v"(B[i]), "+v"(B[i+1]), "+v"(B[i+2]), \
    "+v"(B[i+3]), "+v"(B[i+4]), "+v"(B[i+5]), "+v"(B[i+6]), "+v"(B[i+7]))
#define PIN32(B) do { PIN8(B,0); PIN8(B,8); PIN8(B,16); PIN8(B,24); } while (0)

__global__ __launch_bounds__(256) void cvt_kernel(const float* __restrict__ src,
                                                  u16* __restrict__ dst, int n) {
  int stride = gridDim.x * blockDim.x * 4;
  for (int i = (blockIdx.x * blockDim.x + threadIdx.x) * 4; i < n; i += stride) {
    float4 v = *reinterpret_cast<const float4*>(src + i);
    ushort4 o;
    o.x = f2bf(v.x); o.y = f2bf(v.y); o.z = f2bf(v.z); o.w = f2bf(v.w);
    *reinterpret_cast<ushort4*>(dst + i) = o;
  }
}

// Stage 1: u = x @ W_in^T + b_in -> fp32 into d_out[t]
__global__ __launch_bounds__(256) void stage1_gemm(const u16* __restrict__ A,
                                                   const u16* __restrict__ Bw,
                                                   const float* __restrict__ b_in,
                                                   float* __restrict__ C) {
  __shared__ __align__(16) u16 As[128 * 32];
  __shared__ __align__(16) u16 Bs[128 * 32];
  const int tid  = threadIdx.x;
  const int lane = tid & 63;
  const int wid  = tid >> 6;
  const int wr   = wid >> 1, wc = wid & 1;
  const int bm0  = blockIdx.x * 128;
  const int bn0  = blockIdx.y * 128;
  const int rl   = lane & 15;
  const int kl   = (lane >> 4) * 8;

  f32x4 acc[4][4];
  for (int mi = 0; mi < 4; ++mi)
    for (int ni = 0; ni < 4; ++ni)
      acc[mi][ni] = (f32x4){0.f, 0.f, 0.f, 0.f};

  for (int kt = 0; kt < I_SZ / 32; ++kt) {
    const int k0 = kt * 32;
    __syncthreads();
    for (int t2 = 0; t2 < 2; ++t2) {
      int c = t2 * 256 + tid;
      int row = c >> 2, c8 = c & 3;
      GLDS16(A  + (size_t)(bm0 + row) * I_SZ + k0 + c8 * 8, As + c * 8);
      GLDS16(Bw + (size_t)(bn0 + row) * I_SZ + k0 + c8 * 8, Bs + c * 8);
    }
    __syncthreads();
    bf16x8 af[4], bfv[4];
    for (int mi = 0; mi < 4; ++mi)
      af[mi] = *reinterpret_cast<const bf16x8*>(&As[(wr * 64 + mi * 16 + rl) * 32 + kl]);
    for (int ni = 0; ni < 4; ++ni)
      bfv[ni] = *reinterpret_cast<const bf16x8*>(&Bs[(wc * 64 + ni * 16 + rl) * 32 + kl]);
    for (int mi = 0; mi < 4; ++mi)
      for (int ni = 0; ni < 4; ++ni)
        acc[mi][ni] = __builtin_amdgcn_mfma_f32_16x16x32_bf16(af[mi], bfv[ni], acc[mi][ni], 0, 0, 0);
  }

  const int rh = (lane >> 4) * 4;
  for (int ni = 0; ni < 4; ++ni) {
    int col = bn0 + wc * 64 + ni * 16 + rl;
    float bi = b_in[col];
    for (int mi = 0; mi < 4; ++mi) {
      int row = bm0 + wr * 64 + mi * 16 + rh;
      f32x4 c = acc[mi][ni];
      for (int r = 0; r < 4; ++r)
        C[(size_t)(row + r) * H_SZ + col] = c[r] + bi;
    }
  }
}

// Persistent recurrence (round-5 structure; staging loads de-serialized).
// 256 blocks = 16 batch-groups x 16 col-groups. Sync via __hip_atomic_*
// relaxed AGENT (proven). Data staging via plain global_load_dwordx4 sc0 sc1
// (same MALL-read semantics as the atomic loads, but 8 in flight, one wait).
__global__ __launch_bounds__(256, 1) void rnn_persistent(
    const u16* __restrict__ Whh, const float* __restrict__ b_hh,
    float* __restrict__ out, u16* __restrict__ hb0, u16* __restrict__ hb1,
    u32* __restrict__ slots_base) {
  __shared__ __align__(16) u16 As[16 * 1024];  // 32KB h-tile, XOR-swizzled

  const int b   = blockIdx.x;
  const int mg  = ((b & 7) << 1) | ((b >> 3) & 1);  // batch-group
  const int ng  = b >> 4;                           // col-group
  const int bm0 = mg * 16;
  const int bn0 = ng * 64;
  const int tid = threadIdx.x, lane = tid & 63, wid = tid >> 6;
  const int rl  = lane & 15, kq = lane >> 4;

  u32* slots = slots_base + mg * 64;   // 64 slots: one per (ng, wave)
  const int sidx = ng * 4 + wid;

  // W fragments in registers: wave's 16 hidden cols x K=1024 (128 VGPRs)
  const int wcol = bn0 + wid * 16 + rl;
  bf16x8 Breg[32];
#pragma unroll
  for (int kc = 0; kc < 32; ++kc)
    Breg[kc] = *reinterpret_cast<const bf16x8*>(Whh + (size_t)wcol * H_SZ + kc * 32 + kq * 8);
  PIN32(Breg);

  const int row = bm0 + rl;                  // batch row (D col dim)
  const int c0  = bn0 + wid * 16 + kq * 4;   // 4 consecutive hidden cols (D rows)
  const float4 bh4 = *reinterpret_cast<const float4*>(b_hh + c0);

  float4 hprev = {0.f, 0.f, 0.f, 0.f};
  float4 u = *reinterpret_cast<const float4*>(out + (size_t)row * H_SZ + c0);  // u_0
  const char* Asb = (const char*)As;

  const int wb = (tid & 127) * 16;  // in-row byte offset of this thread's chunks
  const int rb = tid >> 7;          // row parity within chunk pair

  for (int t = 0; t < T_LEN; ++t) {
    const u16* hin = (t & 1) ? hb1 : hb0;
    u16* hout      = (t & 1) ? hb0 : hb1;

    PIN32(Breg);  // force W resident across the staging pressure spike

    // ---- stage h tile (16 x 1024 bf16 = 32KB): 8 pipelined 16B MALL-coherent
    // loads per thread, ONE vmcnt, then swizzled ds_write_b128.
    u32x4 sv[8];
    const char* hinb = (const char*)hin;
#pragma unroll
    for (int i = 0; i < 8; ++i) {
      int r_ = 2 * i + rb;
      const void* src = hinb + (size_t)(bm0 + r_) * 2048 + wb;
      asm volatile("global_load_dwordx4 %0, %1, off sc0 sc1"
                   : "=v"(sv[i]) : "v"(src) : "memory");
    }
    asm volatile("s_waitcnt vmcnt(0)" ::: "memory");
    __builtin_amdgcn_sched_barrier(0);
#pragma unroll
    for (int i = 0; i < 8; ++i) {
      int r_ = 2 * i + rb;
      int dst = r_ * 2048 + (wb ^ ((r_ & 7) << 4));   // swizzled LDS write
      *reinterpret_cast<u32x4*>((char*)As + dst) = sv[i];
    }
    __syncthreads();

    // prefetch u_{t+1} (plain cached; t=511 touches final-h region, unused)
    float4 un = *reinterpret_cast<const float4*>(
        out + (size_t)(t + 1) * (B_SZ * H_SZ) + (size_t)row * H_SZ + c0);

    PIN32(Breg);  // and again right before the MFMA loop

    // ---- MFMA: D = W x h^T (swapped args); lane -> (1 batch row, 4 cols)
    f32x4 acc0 = (f32x4){0.f, 0.f, 0.f, 0.f};
    f32x4 acc1 = (f32x4){0.f, 0.f, 0.f, 0.f};
#pragma unroll
    for (int kc = 0; kc < 32; kc += 2) {
      bf16x8 a0 = *reinterpret_cast<const bf16x8*>(
          Asb + rl * 2048 + ((kc * 64 + kq * 16) ^ ((rl & 7) << 4)));
      acc0 = __builtin_amdgcn_mfma_f32_16x16x32_bf16(Breg[kc], a0, acc0, 0, 0, 0);
      bf16x8 a1 = *reinterpret_cast<const bf16x8*>(
          Asb + rl * 2048 + (((kc + 1) * 64 + kq * 16) ^ ((rl & 7) << 4)));
      acc1 = __builtin_amdgcn_mfma_f32_16x16x32_bf16(Breg[kc + 1], a1, acc1, 0, 0, 0);
    }

    // ---- epilogue: h first (8B atomic store), drain, post; fp32 stores after
    float hv[4];
#pragma unroll
    for (int r = 0; r < 4; ++r) {
      float pre = (&u.x)[r] + acc0[r] + acc1[r] + (&bh4.x)[r];
      float hn  = fmaxf(pre, 0.f);
      float h   = (&hprev.x)[r] * 0.9f + hn * 0.1f;
      (&hprev.x)[r] = h;
      hv[r] = h;
    }
    u32 lo = (u32)f2bf(hv[0]) | ((u32)f2bf(hv[1]) << 16);
    u32 hi = (u32)f2bf(hv[2]) | ((u32)f2bf(hv[3]) << 16);
    u64 pk = (u64)lo | ((u64)hi << 32);
    __hip_atomic_store(reinterpret_cast<u64*>(hout + (size_t)row * H_SZ + c0), pk,
                       __ATOMIC_RELAXED, __HIP_MEMORY_SCOPE_AGENT);
    if (t < T_LEN - 1) {
      asm volatile("s_waitcnt vmcnt(0)" ::: "memory");  // drain h store (+ leftovers)
      if (lane == 0)
        __hip_atomic_store(&slots[sidx], (u32)(t + 1), __ATOMIC_RELAXED, __HIP_MEMORY_SCOPE_AGENT);
    }

    // off-critical-path fp32 stores overlap with the poll below
    float4 ho = {hv[0], hv[1], hv[2], hv[3]};
    *reinterpret_cast<float4*>(out + (size_t)t * (B_SZ * H_SZ) +
                               (size_t)row * H_SZ + c0) = ho;
    if (t == T_LEN - 1)
      *reinterpret_cast<float4*>(out + (size_t)T_LEN * (B_SZ * H_SZ) +
                                 (size_t)row * H_SZ + c0) = ho;
    u = un;

    // ---- poll: wait until all 64 (ng,wave) slots posted step t+1
    if (t < T_LEN - 1) {
      for (;;) {
        u32 v = __hip_atomic_load(&slots[lane], __ATOMIC_RELAXED, __HIP_MEMORY_SCOPE_AGENT);
        if (__all(v > (u32)t)) break;
        __builtin_amdgcn_s_sleep(1);
      }
      __builtin_amdgcn_sched_barrier(0);
    }
  }
}

extern "C" void kernel_launch(void* const* d_in, const int* in_sizes, int n_in,
                              void* d_out, int out_size, void* d_ws, size_t ws_size,
                              hipStream_t stream) {
  const float* x    = (const float*)d_in[0];
  const float* W_in = (const float*)d_in[1];
  const float* b_in = (const float*)d_in[2];
  const float* W_hh = (const float*)d_in[3];
  const float* b_hh = (const float*)d_in[4];
  float* out = (float*)d_out;

  // workspace layout (bytes). slot array overlaps xb (xb dead after stage1).
  const size_t off_xb  = 0;                       // 512*256*256 bf16 = 67108864
  const size_t off_wib = 67108864;                // 1024*256  bf16
  const size_t off_whb = 67633152;                // 1024*1024 bf16
  const size_t off_hb0 = 69730304;                // 256*1024  bf16
  const size_t off_hb1 = 70254592;
  const size_t need    = 70778880;
  if (ws_size < need) return;

  char* ws = (char*)d_ws;
  u16* xb    = (u16*)(ws + off_xb);
  u16* wib   = (u16*)(ws + off_wib);
  u16* whb   = (u16*)(ws + off_whb);
  u16* hb0   = (u16*)(ws + off_hb0);
  u16* hb1   = (u16*)(ws + off_hb1);
  u32* slots = (u32*)(ws + 0);                    // 16 groups * 64 slots * 4B = 4KB

  cvt_kernel<<<1024, 256, 0, stream>>>(x,    xb,  T_LEN * B_SZ * I_SZ);
  cvt_kernel<<<64,   256, 0, stream>>>(W_in, wib, H_SZ * I_SZ);
  cvt_kernel<<<256,  256, 0, stream>>>(W_hh, whb, H_SZ * H_SZ);
  hipMemsetAsync(hb0, 0, (size_t)B_SZ * H_SZ * sizeof(u16), stream);

  dim3 g1(T_LEN * B_SZ / 128, H_SZ / 128);
  stage1_gemm<<<g1, 256, 0, stream>>>(xb, wib, b_in, out);

  // slots overlap xb -> init after stage1 (stream-ordered)
  hipMemsetAsync(slots, 0, NGRP * 64 * sizeof(u32), stream);

  rnn_persistent<<<256, 256, 0, stream>>>(whb, b_hh, out, hb0, hb1, slots);
}

// Round 8
// 1341.782 us; speedup vs baseline: 3.0013x; 3.0013x over previous
//
#include <hip/hip_runtime.h>
#include <hip/hip_bf16.h>
#include <stdint.h>
#include <stddef.h>

#define T_LEN 512
#define B_SZ  256
#define I_SZ  256
#define H_SZ  1024
#define NGRP  16   // blocks per barrier group (one batch-group)

typedef __attribute__((ext_vector_type(8))) short bf16x8;
typedef __attribute__((ext_vector_type(4))) float f32x4;
typedef __attribute__((ext_vector_type(4))) unsigned int u32x4;
typedef unsigned short u16;
typedef unsigned int   u32;
typedef unsigned long long u64;

__device__ inline u16 f2bf(float f) {
  union { float f; u32 u; } x; x.f = f;
  u32 r = x.u + 0x7fffu + ((x.u >> 16) & 1u);
  return (u16)(r >> 16);
}

#define GLDS16(gp, lp) __builtin_amdgcn_global_load_lds( \
    (const __attribute__((address_space(1))) u32*)(gp),  \
    (__attribute__((address_space(3))) u32*)(lp), 16, 0, 0)

// keep 8 bf16x8 values pinned in VGPRs (0 instructions)
#define PIN8(B, i) asm volatile("" : "+v"(B[i]), "+v"(B[i+1]), "+v"(B[i+2]), \
    "+v"(B[i+3]), "+v"(B[i+4]), "+v"(B[i+5]), "+v"(B[i+6]), "+v"(B[i+7]))
#define PIN32(B) do { PIN8(B,0); PIN8(B,8); PIN8(B,16); PIN8(B,24); } while (0)

struct GCnt { u32 v; u32 pad[31]; };  // one 128B line per group counter

__global__ __launch_bounds__(256) void cvt_kernel(const float* __restrict__ src,
                                                  u16* __restrict__ dst, int n) {
  int stride = gridDim.x * blockDim.x * 4;
  for (int i = (blockIdx.x * blockDim.x + threadIdx.x) * 4; i < n; i += stride) {
    float4 v = *reinterpret_cast<const float4*>(src + i);
    ushort4 o;
    o.x = f2bf(v.x); o.y = f2bf(v.y); o.z = f2bf(v.z); o.w = f2bf(v.w);
    *reinterpret_cast<ushort4*>(dst + i) = o;
  }
}

// Stage 1: u = x @ W_in^T + b_in -> fp32 into d_out[t]
__global__ __launch_bounds__(256) void stage1_gemm(const u16* __restrict__ A,
                                                   const u16* __restrict__ Bw,
                                                   const float* __restrict__ b_in,
                                                   float* __restrict__ C) {
  __shared__ __align__(16) u16 As[128 * 32];
  __shared__ __align__(16) u16 Bs[128 * 32];
  const int tid  = threadIdx.x;
  const int lane = tid & 63;
  const int wid  = tid >> 6;
  const int wr   = wid >> 1, wc = wid & 1;
  const int bm0  = blockIdx.x * 128;
  const int bn0  = blockIdx.y * 128;
  const int rl   = lane & 15;
  const int kl   = (lane >> 4) * 8;

  f32x4 acc[4][4];
  for (int mi = 0; mi < 4; ++mi)
    for (int ni = 0; ni < 4; ++ni)
      acc[mi][ni] = (f32x4){0.f, 0.f, 0.f, 0.f};

  for (int kt = 0; kt < I_SZ / 32; ++kt) {
    const int k0 = kt * 32;
    __syncthreads();
    for (int t2 = 0; t2 < 2; ++t2) {
      int c = t2 * 256 + tid;
      int row = c >> 2, c8 = c & 3;
      GLDS16(A  + (size_t)(bm0 + row) * I_SZ + k0 + c8 * 8, As + c * 8);
      GLDS16(Bw + (size_t)(bn0 + row) * I_SZ + k0 + c8 * 8, Bs + c * 8);
    }
    __syncthreads();
    bf16x8 af[4], bfv[4];
    for (int mi = 0; mi < 4; ++mi)
      af[mi] = *reinterpret_cast<const bf16x8*>(&As[(wr * 64 + mi * 16 + rl) * 32 + kl]);
    for (int ni = 0; ni < 4; ++ni)
      bfv[ni] = *reinterpret_cast<const bf16x8*>(&Bs[(wc * 64 + ni * 16 + rl) * 32 + kl]);
    for (int mi = 0; mi < 4; ++mi)
      for (int ni = 0; ni < 4; ++ni)
        acc[mi][ni] = __builtin_amdgcn_mfma_f32_16x16x32_bf16(af[mi], bfv[ni], acc[mi][ni], 0, 0, 0);
  }

  const int rh = (lane >> 4) * 4;
  for (int ni = 0; ni < 4; ++ni) {
    int col = bn0 + wc * 64 + ni * 16 + rl;
    float bi = b_in[col];
    for (int mi = 0; mi < 4; ++mi) {
      int row = bm0 + wr * 64 + mi * 16 + rh;
      f32x4 c = acc[mi][ni];
      for (int r = 0; r < 4; ++r)
        C[(size_t)(row + r) * H_SZ + col] = c[r] + bi;
    }
  }
}

// Persistent recurrence (round-6 base; sync protocol replaced).
// 256 blocks = 16 batch-groups x 16 col-groups. Per step, per group:
// each block posts ONE __hip_atomic_fetch_add to the group counter (after
// __syncthreads has drained all waves' h-stores), and ONLY tid0 polls the
// counter; __syncthreads broadcasts the release. ~256x less MALL poll traffic
// than the 64-slot/all-lane scheme. All sync via proven __hip_atomic_*.
__global__ __launch_bounds__(256, 1) void rnn_persistent(
    const u16* __restrict__ Whh, const float* __restrict__ b_hh,
    float* __restrict__ out, u16* __restrict__ hb0, u16* __restrict__ hb1,
    GCnt* __restrict__ cnts) {
  __shared__ __align__(16) u16 As[16 * 1024];  // 32KB h-tile, XOR-swizzled

  const int b   = blockIdx.x;
  const int mg  = ((b & 7) << 1) | ((b >> 3) & 1);  // batch-group
  const int ng  = b >> 4;                           // col-group (unused in sync now)
  const int bm0 = mg * 16;
  const int bn0 = ng * 64;
  const int tid = threadIdx.x, lane = tid & 63, wid = tid >> 6;
  const int rl  = lane & 15, kq = lane >> 4;

  u32* cnt = &cnts[mg].v;

  // W fragments in registers: wave's 16 hidden cols x K=1024 (128 VGPRs)
  const int wcol = bn0 + wid * 16 + rl;
  bf16x8 Breg[32];
#pragma unroll
  for (int kc = 0; kc < 32; ++kc)
    Breg[kc] = *reinterpret_cast<const bf16x8*>(Whh + (size_t)wcol * H_SZ + kc * 32 + kq * 8);
  PIN32(Breg);

  const int row = bm0 + rl;                  // batch row (D col dim)
  const int c0  = bn0 + wid * 16 + kq * 4;   // 4 consecutive hidden cols (D rows)
  const float4 bh4 = *reinterpret_cast<const float4*>(b_hh + c0);

  float4 hprev = {0.f, 0.f, 0.f, 0.f};
  float4 u = *reinterpret_cast<const float4*>(out + (size_t)row * H_SZ + c0);  // u_0
  const char* Asb = (const char*)As;

  const int wb = (tid & 127) * 16;  // in-row byte offset of this thread's chunks
  const int rb = tid >> 7;          // row parity within chunk pair

  for (int t = 0; t < T_LEN; ++t) {
    const u16* hin = (t & 1) ? hb1 : hb0;
    u16* hout      = (t & 1) ? hb0 : hb1;

    PIN32(Breg);

    // ---- stage h tile (16 x 1024 bf16 = 32KB): 8 x 16B coherent loads,
    // one wait, swizzled ds_write_b128. (Data path proven in r6.)
    u32x4 sv[8];
    const char* hinb = (const char*)hin;
#pragma unroll
    for (int i = 0; i < 8; ++i) {
      int r_ = 2 * i + rb;
      const void* src = hinb + (size_t)(bm0 + r_) * 2048 + wb;
      asm volatile("global_load_dwordx4 %0, %1, off sc0 sc1"
                   : "=v"(sv[i]) : "v"(src) : "memory");
    }
    asm volatile("s_waitcnt vmcnt(0)" ::: "memory");
    __builtin_amdgcn_sched_barrier(0);
#pragma unroll
    for (int i = 0; i < 8; ++i) {
      int r_ = 2 * i + rb;
      int dst = r_ * 2048 + (wb ^ ((r_ & 7) << 4));   // swizzled LDS write
      *reinterpret_cast<u32x4*>((char*)As + dst) = sv[i];
    }
    __syncthreads();

    // prefetch u_{t+1} (plain cached; t=511 touches final-h region, unused)
    float4 un = *reinterpret_cast<const float4*>(
        out + (size_t)(t + 1) * (B_SZ * H_SZ) + (size_t)row * H_SZ + c0);

    PIN32(Breg);

    // ---- MFMA: D = W x h^T; lane -> (1 batch row, 4 consecutive cols)
    f32x4 acc0 = (f32x4){0.f, 0.f, 0.f, 0.f};
    f32x4 acc1 = (f32x4){0.f, 0.f, 0.f, 0.f};
#pragma unroll
    for (int kc = 0; kc < 32; kc += 2) {
      bf16x8 a0 = *reinterpret_cast<const bf16x8*>(
          Asb + rl * 2048 + ((kc * 64 + kq * 16) ^ ((rl & 7) << 4)));
      acc0 = __builtin_amdgcn_mfma_f32_16x16x32_bf16(Breg[kc], a0, acc0, 0, 0, 0);
      bf16x8 a1 = *reinterpret_cast<const bf16x8*>(
          Asb + rl * 2048 + (((kc + 1) * 64 + kq * 16) ^ ((rl & 7) << 4)));
      acc1 = __builtin_amdgcn_mfma_f32_16x16x32_bf16(Breg[kc + 1], a1, acc1, 0, 0, 0);
    }

    // ---- epilogue: compute h, store bf16 h (agent atomic)
    float hv[4];
#pragma unroll
    for (int r = 0; r < 4; ++r) {
      float pre = (&u.x)[r] + acc0[r] + acc1[r] + (&bh4.x)[r];
      float hn  = fmaxf(pre, 0.f);
      float h   = (&hprev.x)[r] * 0.9f + hn * 0.1f;
      (&hprev.x)[r] = h;
      hv[r] = h;
    }
    u32 lo = (u32)f2bf(hv[0]) | ((u32)f2bf(hv[1]) << 16);
    u32 hi = (u32)f2bf(hv[2]) | ((u32)f2bf(hv[3]) << 16);
    u64 pk = (u64)lo | ((u64)hi << 32);
    __hip_atomic_store(reinterpret_cast<u64*>(hout + (size_t)row * H_SZ + c0), pk,
                       __ATOMIC_RELAXED, __HIP_MEMORY_SCOPE_AGENT);

    // ---- post: barrier drains every wave's vmcnt (h-stores acked), then
    // ONE fetch_add per block
    __syncthreads();
    if (t < T_LEN - 1 && tid == 0)
      __hip_atomic_fetch_add(cnt, 1u, __ATOMIC_RELAXED, __HIP_MEMORY_SCOPE_AGENT);

    // off-critical-path fp32 stores overlap the leader's poll
    float4 ho = {hv[0], hv[1], hv[2], hv[3]};
    *reinterpret_cast<float4*>(out + (size_t)t * (B_SZ * H_SZ) +
                               (size_t)row * H_SZ + c0) = ho;
    if (t == T_LEN - 1)
      *reinterpret_cast<float4*>(out + (size_t)T_LEN * (B_SZ * H_SZ) +
                                 (size_t)row * H_SZ + c0) = ho;
    u = un;

    // ---- leader poll: counter reaches NGRP*(t+1) when whole group posted
    if (t < T_LEN - 1) {
      if (tid == 0) {
        const u32 tgt = (u32)(NGRP * (t + 1));
        while (__hip_atomic_load(cnt, __ATOMIC_RELAXED, __HIP_MEMORY_SCOPE_AGENT) < tgt) {
        }
      }
      __syncthreads();
      __builtin_amdgcn_sched_barrier(0);
    }
  }
}

extern "C" void kernel_launch(void* const* d_in, const int* in_sizes, int n_in,
                              void* d_out, int out_size, void* d_ws, size_t ws_size,
                              hipStream_t stream) {
  const float* x    = (const float*)d_in[0];
  const float* W_in = (const float*)d_in[1];
  const float* b_in = (const float*)d_in[2];
  const float* W_hh = (const float*)d_in[3];
  const float* b_hh = (const float*)d_in[4];
  float* out = (float*)d_out;

  // workspace layout (bytes). counter array overlaps xb (dead after stage1).
  const size_t off_xb  = 0;                       // 512*256*256 bf16 = 67108864
  const size_t off_wib = 67108864;                // 1024*256  bf16
  const size_t off_whb = 67633152;                // 1024*1024 bf16
  const size_t off_hb0 = 69730304;                // 256*1024  bf16
  const size_t off_hb1 = 70254592;
  const size_t need    = 70778880;
  if (ws_size < need) return;

  char* ws = (char*)d_ws;
  u16* xb   = (u16*)(ws + off_xb);
  u16* wib  = (u16*)(ws + off_wib);
  u16* whb  = (u16*)(ws + off_whb);
  u16* hb0  = (u16*)(ws + off_hb0);
  u16* hb1  = (u16*)(ws + off_hb1);
  GCnt* cnts = (GCnt*)(ws + 0);                   // 16 * 128B = 2KB

  cvt_kernel<<<1024, 256, 0, stream>>>(x,    xb,  T_LEN * B_SZ * I_SZ);
  cvt_kernel<<<64,   256, 0, stream>>>(W_in, wib, H_SZ * I_SZ);
  cvt_kernel<<<256,  256, 0, stream>>>(W_hh, whb, H_SZ * H_SZ);
  hipMemsetAsync(hb0, 0, (size_t)B_SZ * H_SZ * sizeof(u16), stream);

  dim3 g1(T_LEN * B_SZ / 128, H_SZ / 128);
  stage1_gemm<<<g1, 256, 0, stream>>>(xb, wib, b_in, out);

  // counters overlap xb -> init after stage1 (stream-ordered)
  hipMemsetAsync(cnts, 0, NGRP * sizeof(GCnt), stream);

  rnn_persistent<<<256, 256, 0, stream>>>(whb, b_hh, out, hb0, hb1, cnts);
}